// Round 1
// baseline (67.681 us; speedup 1.0000x reference)
//
#include <hip/hip_runtime.h>

#define DD 2048
#define MHH 32

// y[row] = relu(dot(W[row,:], x) + b[row]); one wave (64 lanes) per row.
__global__ __launch_bounds__(256) void gemv_relu_k(const float* __restrict__ W,
                                                   const float* __restrict__ x,
                                                   const float* __restrict__ b,
                                                   float* __restrict__ y) {
    const int wave = threadIdx.x >> 6;
    const int lane = threadIdx.x & 63;
    const int row  = (blockIdx.x << 2) + wave;
    const float* Wr = W + (size_t)row * DD;
    float acc = 0.f;
#pragma unroll
    for (int it = 0; it < 8; ++it) {
        const int col = ((it << 6) + lane) << 2;       // float4 index, coalesced
        const float4 w4 = *reinterpret_cast<const float4*>(Wr + col);
        const float4 x4 = *reinterpret_cast<const float4*>(x + col);
        acc = fmaf(w4.x, x4.x, acc);
        acc = fmaf(w4.y, x4.y, acc);
        acc = fmaf(w4.z, x4.z, acc);
        acc = fmaf(w4.w, x4.w, acc);
    }
#pragma unroll
    for (int off = 32; off > 0; off >>= 1)
        acc += __shfl_down(acc, off, 64);
    if (lane == 0) {
        const float v = acc + b[row];
        y[row] = fmaxf(v, 0.f);
    }
}

// nW[o,i] = sum_m relu(inp[i]*Wm1[0,m] + W[o,i]*Wm1[1,m] + outp[o]*Wm1[2,m] + bm1[m]) * Wm2[m] + bm2
// One block per (layer,row); P[m] = bm1[m] + outp[o]*Wm1[2,m] hoisted per block.
__global__ __launch_bounds__(256) void meta_k(const float* __restrict__ W1,
                                              const float* __restrict__ W2,
                                              const float* __restrict__ W3,
                                              const float* __restrict__ a0,
                                              const float* __restrict__ a1,
                                              const float* __restrict__ a2,
                                              const float* __restrict__ a3,
                                              const float* __restrict__ Wm1,
                                              const float* __restrict__ bm1,
                                              const float* __restrict__ Wm2,
                                              const float* __restrict__ bm2,
                                              float* __restrict__ nW) {
    const int layer = blockIdx.x >> 11;          // 2048 rows per layer
    const int row   = blockIdx.x & (DD - 1);

    const float* W   = (layer == 0) ? W1 : (layer == 1) ? W2 : W3;
    const float* inp = (layer == 0) ? a0 : (layer == 1) ? a1 : a2;
    const float* oup = (layer == 0) ? a1 : (layer == 1) ? a2 : a3;

    const float ov = oup[row];
    float A[MHH], B[MHH], P[MHH], V2[MHH];
#pragma unroll
    for (int m = 0; m < MHH; ++m) {
        A[m]  = Wm1[m];                 // Wm1[0,m]
        B[m]  = Wm1[MHH + m];           // Wm1[1,m]
        P[m]  = fmaf(ov, Wm1[2 * MHH + m], bm1[m]);
        V2[m] = Wm2[m];
    }
    const float bias2 = bm2[0];

    const float* Wr  = W  + (size_t)row * DD;
    float*       nWr = nW + (size_t)layer * DD * DD + (size_t)row * DD;

#pragma unroll
    for (int half = 0; half < 2; ++half) {
        const int col = half * (DD / 2) + threadIdx.x * 4;   // coalesced float4
        const float4 w4 = *reinterpret_cast<const float4*>(Wr + col);
        const float4 u4 = *reinterpret_cast<const float4*>(inp + col);
        float acc0 = 0.f, acc1 = 0.f, acc2 = 0.f, acc3 = 0.f;
#pragma unroll
        for (int m = 0; m < MHH; ++m) {
            float t0 = fmaf(u4.x, A[m], P[m]);
            float t1 = fmaf(u4.y, A[m], P[m]);
            float t2 = fmaf(u4.z, A[m], P[m]);
            float t3 = fmaf(u4.w, A[m], P[m]);
            t0 = fmaf(w4.x, B[m], t0);
            t1 = fmaf(w4.y, B[m], t1);
            t2 = fmaf(w4.z, B[m], t2);
            t3 = fmaf(w4.w, B[m], t3);
            t0 = fmaxf(t0, 0.f);
            t1 = fmaxf(t1, 0.f);
            t2 = fmaxf(t2, 0.f);
            t3 = fmaxf(t3, 0.f);
            acc0 = fmaf(t0, V2[m], acc0);
            acc1 = fmaf(t1, V2[m], acc1);
            acc2 = fmaf(t2, V2[m], acc2);
            acc3 = fmaf(t3, V2[m], acc3);
        }
        float4 r;
        r.x = acc0 + bias2;
        r.y = acc1 + bias2;
        r.z = acc2 + bias2;
        r.w = acc3 + bias2;
        *reinterpret_cast<float4*>(nWr + col) = r;
    }
}

extern "C" void kernel_launch(void* const* d_in, const int* in_sizes, int n_in,
                              void* d_out, int out_size, void* d_ws, size_t ws_size,
                              hipStream_t stream) {
    const float* x   = (const float*)d_in[0];
    const float* W1  = (const float*)d_in[1];
    const float* b1  = (const float*)d_in[2];
    const float* W2  = (const float*)d_in[3];
    const float* b2  = (const float*)d_in[4];
    const float* W3  = (const float*)d_in[5];
    const float* b3  = (const float*)d_in[6];
    const float* Wm1 = (const float*)d_in[7];
    const float* bm1 = (const float*)d_in[8];
    const float* Wm2 = (const float*)d_in[9];
    const float* bm2 = (const float*)d_in[10];

    float* out = (float*)d_out;            // out: [2048]
    float* nW  = out + DD;                 // nW1|nW2|nW3: 3 x 2048 x 2048
    float* a1  = (float*)d_ws;             // [2048]
    float* a2  = a1 + DD;                  // [2048]

    gemv_relu_k<<<DD / 4, 256, 0, stream>>>(W1, x,  b1, a1);
    gemv_relu_k<<<DD / 4, 256, 0, stream>>>(W2, a1, b2, a2);
    gemv_relu_k<<<DD / 4, 256, 0, stream>>>(W3, a2, b3, out);
    meta_k<<<3 * DD, 256, 0, stream>>>(W1, W2, W3, x, a1, a2, out,
                                       Wm1, bm1, Wm2, bm2, nW);
}

// Round 2
// 61.628 us; speedup vs baseline: 1.0982x; 1.0982x over previous
//
#include <hip/hip_runtime.h>

#define DD 2048
#define MHH 32

// y[row] = relu(dot(W[row,:], x) + b[row]); one wave (64 lanes) per row.
__global__ __launch_bounds__(256) void gemv_relu_k(const float* __restrict__ W,
                                                   const float* __restrict__ x,
                                                   const float* __restrict__ b,
                                                   float* __restrict__ y) {
    const int wave = threadIdx.x >> 6;
    const int lane = threadIdx.x & 63;
    const int row  = (blockIdx.x << 2) + wave;
    const float* Wr = W + (size_t)row * DD;
    float acc = 0.f;
#pragma unroll
    for (int it = 0; it < 8; ++it) {
        const int col = ((it << 6) + lane) << 2;       // float4 index, coalesced
        const float4 w4 = *reinterpret_cast<const float4*>(Wr + col);
        const float4 x4 = *reinterpret_cast<const float4*>(x + col);
        acc = fmaf(w4.x, x4.x, acc);
        acc = fmaf(w4.y, x4.y, acc);
        acc = fmaf(w4.z, x4.z, acc);
        acc = fmaf(w4.w, x4.w, acc);
    }
#pragma unroll
    for (int off = 32; off > 0; off >>= 1)
        acc += __shfl_down(acc, off, 64);
    if (lane == 0) {
        const float v = acc + b[row];
        y[row] = fmaxf(v, 0.f);
    }
}

// nW[o,i] = sum_m relu(inp[i]*Wm1[0,m] + W[o,i]*Wm1[1,m] + outp[o]*Wm1[2,m] + bm1[m]) * Wm2[m] + bm2
// One block per (layer,row). Inner loop engineered to exactly 4 VALU ops per
// (element, m): v_fma(u, A[m], P[m]) with P pinned in VGPR (so at most one
// SGPR operand per instruction), v_fmac(w, B[m]), v_max(t, 0), v_fmac(t, V2[m]).
__global__ __launch_bounds__(256, 1) void meta_k(const float* __restrict__ W1,
                                                 const float* __restrict__ W2,
                                                 const float* __restrict__ W3,
                                                 const float* __restrict__ a0,
                                                 const float* __restrict__ a1,
                                                 const float* __restrict__ a2,
                                                 const float* __restrict__ a3,
                                                 const float* __restrict__ Wm1,
                                                 const float* __restrict__ bm1,
                                                 const float* __restrict__ Wm2,
                                                 const float* __restrict__ bm2,
                                                 float* __restrict__ nW) {
    const int layer = blockIdx.x >> 11;          // 2048 rows per layer
    const int row   = blockIdx.x & (DD - 1);

    const float* W   = (layer == 0) ? W1 : (layer == 1) ? W2 : W3;
    const float* inp = (layer == 0) ? a0 : (layer == 1) ? a1 : a2;
    const float* oup = (layer == 0) ? a1 : (layer == 1) ? a2 : a3;

    const float* Wr  = W  + (size_t)row * DD;
    float*       nWr = nW + (size_t)layer * DD * DD + (size_t)row * DD;

    // Hoist all global loads before the compute block.
    const int col0 = threadIdx.x * 4;            // first half
    const int col1 = (DD / 2) + threadIdx.x * 4; // second half
    const float4 w4a = *reinterpret_cast<const float4*>(Wr + col0);
    const float4 u4a = *reinterpret_cast<const float4*>(inp + col0);
    const float4 w4b = *reinterpret_cast<const float4*>(Wr + col1);
    const float4 u4b = *reinterpret_cast<const float4*>(inp + col1);

    const float ov = oup[row];

    float A[MHH], B[MHH], P[MHH], V2[MHH];
#pragma unroll
    for (int m = 0; m < MHH; ++m) {
        A[m]  = Wm1[m];                 // Wm1[0,m]
        B[m]  = Wm1[MHH + m];           // Wm1[1,m]
        V2[m] = Wm2[m];
        P[m]  = fmaf(ov, Wm1[2 * MHH + m], bm1[m]);
        // Pin P[m] to a VGPR: it appears alongside A[m] (SGPR) in the same
        // v_fma, and VALU allows only one SGPR operand per instruction.
        asm volatile("" : "+v"(P[m]));
    }
    const float bias2 = bm2[0];

    float c0 = 0.f, c1 = 0.f, c2 = 0.f, c3 = 0.f;
    float c4 = 0.f, c5 = 0.f, c6 = 0.f, c7 = 0.f;

#pragma unroll
    for (int m = 0; m < MHH; ++m) {
        float t0 = fmaf(u4a.x, A[m], P[m]);
        float t1 = fmaf(u4a.y, A[m], P[m]);
        float t2 = fmaf(u4a.z, A[m], P[m]);
        float t3 = fmaf(u4a.w, A[m], P[m]);
        float t4 = fmaf(u4b.x, A[m], P[m]);
        float t5 = fmaf(u4b.y, A[m], P[m]);
        float t6 = fmaf(u4b.z, A[m], P[m]);
        float t7 = fmaf(u4b.w, A[m], P[m]);
        t0 = fmaf(w4a.x, B[m], t0);
        t1 = fmaf(w4a.y, B[m], t1);
        t2 = fmaf(w4a.z, B[m], t2);
        t3 = fmaf(w4a.w, B[m], t3);
        t4 = fmaf(w4b.x, B[m], t4);
        t5 = fmaf(w4b.y, B[m], t5);
        t6 = fmaf(w4b.z, B[m], t6);
        t7 = fmaf(w4b.w, B[m], t7);
        t0 = fmaxf(t0, 0.f);
        t1 = fmaxf(t1, 0.f);
        t2 = fmaxf(t2, 0.f);
        t3 = fmaxf(t3, 0.f);
        t4 = fmaxf(t4, 0.f);
        t5 = fmaxf(t5, 0.f);
        t6 = fmaxf(t6, 0.f);
        t7 = fmaxf(t7, 0.f);
        c0 = fmaf(t0, V2[m], c0);
        c1 = fmaf(t1, V2[m], c1);
        c2 = fmaf(t2, V2[m], c2);
        c3 = fmaf(t3, V2[m], c3);
        c4 = fmaf(t4, V2[m], c4);
        c5 = fmaf(t5, V2[m], c5);
        c6 = fmaf(t6, V2[m], c6);
        c7 = fmaf(t7, V2[m], c7);
    }

    float4 r0, r1;
    r0.x = c0 + bias2; r0.y = c1 + bias2; r0.z = c2 + bias2; r0.w = c3 + bias2;
    r1.x = c4 + bias2; r1.y = c5 + bias2; r1.z = c6 + bias2; r1.w = c7 + bias2;
    *reinterpret_cast<float4*>(nWr + col0) = r0;
    *reinterpret_cast<float4*>(nWr + col1) = r1;
}

extern "C" void kernel_launch(void* const* d_in, const int* in_sizes, int n_in,
                              void* d_out, int out_size, void* d_ws, size_t ws_size,
                              hipStream_t stream) {
    const float* x   = (const float*)d_in[0];
    const float* W1  = (const float*)d_in[1];
    const float* b1  = (const float*)d_in[2];
    const float* W2  = (const float*)d_in[3];
    const float* b2  = (const float*)d_in[4];
    const float* W3  = (const float*)d_in[5];
    const float* b3  = (const float*)d_in[6];
    const float* Wm1 = (const float*)d_in[7];
    const float* bm1 = (const float*)d_in[8];
    const float* Wm2 = (const float*)d_in[9];
    const float* bm2 = (const float*)d_in[10];

    float* out = (float*)d_out;            // out: [2048]
    float* nW  = out + DD;                 // nW1|nW2|nW3: 3 x 2048 x 2048
    float* a1  = (float*)d_ws;             // [2048]
    float* a2  = a1 + DD;                  // [2048]

    gemv_relu_k<<<DD / 4, 256, 0, stream>>>(W1, x,  b1, a1);
    gemv_relu_k<<<DD / 4, 256, 0, stream>>>(W2, a1, b2, a2);
    gemv_relu_k<<<DD / 4, 256, 0, stream>>>(W3, a2, b3, out);
    meta_k<<<3 * DD, 256, 0, stream>>>(W1, W2, W3, x, a1, a2, out,
                                       Wm1, bm1, Wm2, bm2, nW);
}